// Round 4
// baseline (399.335 us; speedup 1.0000x reference)
//
#include <hip/hip_runtime.h>
#include <hip/hip_fp16.h>

// DCell forward, MI355X (gfx950). All inputs/outputs fp32.
// One block per (term, D-chunk) => BatchNorm is block-local.
// Linear bias b{3,2,1,0} cancels inside BatchNorm (z - mean) => never read.
// Key fix this round: gene rows (256 B each, 512/131/32 KB apart per lane) are
// staged cooperatively into LDS as fp16 (genes are exactly 0/1), with 16 lanes
// covering one row contiguously => ~4 txns per wave-inst instead of ~64.
// Children in k_mid (term-major fp16, 40 KB contiguous per term) are staged
// via coalesced uint4 copies.
// ws: [h3 fp16 [t][b][D] | h2 fp16 [t][b][D] | h1 fp32 [b][t][D] | z0] ~= 29 MB.

#define DEV static __device__ __forceinline__

constexpr int B_  = 256, G_ = 64, D_ = 20;
constexpr int T3_ = 2048, T2_ = 512, T1_ = 128;
constexpr float EPS_ = 1e-5f;
constexpr int INM = 4 * D_ + G_;   // 144

constexpr size_t N_H3 = (size_t)T3_ * B_ * D_;   // halfs
constexpr size_t N_H2 = (size_t)T2_ * B_ * D_;   // halfs
constexpr size_t N_H1 = (size_t)B_ * T1_ * D_;   // floats
constexpr size_t OFF_H3B = 0;
constexpr size_t OFF_H2B = OFF_H3B + N_H3 * 2;
constexpr size_t OFF_H1B = OFF_H2B + N_H2 * 2;
constexpr size_t OFF_Z0B = OFF_H1B + N_H1 * 4;

// LDS gene row stride in uints (2 halfs per uint): 32 uints data + 1 pad.
// Read bank step per lane = 33 % 32 = 1 -> conflict-free.
constexpr int GSTRIDE_U = 33;

DEV float fast_tanh(float x) {
    float e = __expf(2.0f * x);
    return fmaf(-2.0f, __builtin_amdgcn_rcpf(e + 1.0f), 1.0f);
}

// Cooperative stage of genes[0:256][t][0:64] fp32 -> LDS fp16.
// 16-lane group loads one 256 B row contiguously (float4 per lane).
DEV void stage_genes(const float* __restrict__ genes_t, size_t rowStrideF,
                     uint* ldsg, int tid) {
    const int e = tid & 15;          // float4 index within row
    const int r0 = tid >> 4;         // 16 rows per iteration
#pragma unroll
    for (int it = 0; it < 16; ++it) {
        const int row = r0 + 16 * it;
        float4 f = ((const float4*)(genes_t + (size_t)row * rowStrideF))[e];
        union { __half2 h2; uint u; } p0, p1;
        p0.h2 = __floats2half2_rn(f.x, f.y);
        p1.h2 = __floats2half2_rn(f.z, f.w);
        ldsg[GSTRIDE_U * row + 2 * e]     = p0.u;
        ldsg[GSTRIDE_U * row + 2 * e + 1] = p1.u;
    }
}

// BN over batch (block-local: 256 threads == 256 batch rows) + tanh.
template <int N>
DEV void bn_tanh(const float (&acc)[N], const float* gterm, const float* beterm,
                 int o0, int tid, float (&h)[N]) {
    __shared__ float sred[4][N], qred[4][N], Avec[N], Cvec[N];
    const int lane = tid & 63, wave = tid >> 6;
    float s[N], q[N];
#pragma unroll
    for (int o = 0; o < N; ++o) { s[o] = acc[o]; q[o] = acc[o] * acc[o]; }
#pragma unroll
    for (int off = 32; off; off >>= 1) {
#pragma unroll
        for (int o = 0; o < N; ++o) {
            s[o] += __shfl_xor(s[o], off, 64);
            q[o] += __shfl_xor(q[o], off, 64);
        }
    }
    if (lane == 0) {
#pragma unroll
        for (int o = 0; o < N; ++o) { sred[wave][o] = s[o]; qred[wave][o] = q[o]; }
    }
    __syncthreads();
    if (tid < N) {
        float S = sred[0][tid] + sred[1][tid] + sred[2][tid] + sred[3][tid];
        float Q = qred[0][tid] + qred[1][tid] + qred[2][tid] + qred[3][tid];
        float mu  = S * (1.0f / B_);
        float var = fmaxf(Q * (1.0f / B_) - mu * mu, 0.0f);
        float rstd = rsqrtf(var + EPS_);
        float A = rstd * gterm[o0 + tid];
        Avec[tid] = A;
        Cvec[tid] = beterm[o0 + tid] - mu * A;
    }
    __syncthreads();
#pragma unroll
    for (int o = 0; o < N; ++o) h[o] = fast_tanh(fmaf(acc[o], Avec[o], Cvec[o]));
}

// ---- stratum 3 (leaves): x = genes (64), out fp16 term-major ----------------
__global__ __launch_bounds__(256, 4) void k_stage3(const float* __restrict__ genes,
                                                   const float* __restrict__ W,
                                                   const float* __restrict__ g,
                                                   const float* __restrict__ be,
                                                   __half* __restrict__ hout) {
    __shared__ uint ldsg[B_ * GSTRIDE_U];
    const int t = blockIdx.x, b = threadIdx.x;
    stage_genes(genes + (size_t)t * G_, (size_t)T3_ * G_, ldsg, b);
    __syncthreads();
    const float* Wt = W + (size_t)t * (G_ * D_);
    float acc[D_] = {};
#pragma unroll
    for (int g2 = 0; g2 < G_ / 2; ++g2) {
        union { uint u; __half2 h2; } pk;
        pk.u = ldsg[GSTRIDE_U * b + g2];
        float x0 = __low2float(pk.h2), x1 = __high2float(pk.h2);
        const float* w0 = Wt + (2 * g2) * D_;
        const float* w1 = w0 + D_;
#pragma unroll
        for (int o = 0; o < D_; ++o) acc[o] = fmaf(x0, w0[o], acc[o]);
#pragma unroll
        for (int o = 0; o < D_; ++o) acc[o] = fmaf(x1, w1[o], acc[o]);
    }
    float h[D_];
    bn_tanh<D_>(acc, g + (size_t)t * D_, be + (size_t)t * D_, 0, b, h);
    uint2* dst = (uint2*)(hout + ((size_t)t * B_ + b) * D_);
#pragma unroll
    for (int v = 0; v < 5; ++v) {
        union { __half2 h2[2]; uint2 u; } pk;
        pk.h2[0] = __floats2half2_rn(h[4 * v],     h[4 * v + 1]);
        pk.h2[1] = __floats2half2_rn(h[4 * v + 2], h[4 * v + 3]);
        dst[v] = pk.u;
    }
}

// ---- strata 2/1: x = [4 fp16 children (80) | genes (64)] --------------------
// grid = T * (D_/DCH). Children staged via coalesced uint4 copy (40 KB contig).
template <int T, int DCH, bool OUT_HALF_TERM_MAJOR>
__global__ __launch_bounds__(256, 2) void k_mid(const __half* __restrict__ hsrc,
                                                const float* __restrict__ genes,
                                                const float* __restrict__ W,
                                                const float* __restrict__ g,
                                                const float* __restrict__ be,
                                                void* __restrict__ hout_) {
    constexpr int NCH = D_ / DCH;
    constexpr int NCH4 = 4 * B_ * D_ / 8;   // child uint4 count = 2560
    __shared__ uint ldsg[B_ * GSTRIDE_U];
    __shared__ uint4 ldsh[NCH4];
    const int t = blockIdx.x / NCH, o0 = (blockIdx.x % NCH) * DCH;
    const int b = threadIdx.x;
    // stage children (coalesced) and genes (row-cooperative) concurrently
    const uint4* csrc = (const uint4*)(hsrc + (size_t)(4 * t) * B_ * D_);
#pragma unroll
    for (int it = 0; it < NCH4 / 256; ++it) ldsh[b + 256 * it] = csrc[b + 256 * it];
    stage_genes(genes + (size_t)t * G_, (size_t)T * G_, ldsg, b);
    __syncthreads();

    const float* Wt = W + (size_t)t * (INM * D_) + o0;
    const __half* hc0 = (const __half*)ldsh;
    float acc[DCH] = {};
#pragma unroll
    for (int c = 0; c < 4; ++c) {
        const __half* hc = hc0 + (size_t)(c * B_ + b) * D_;
#pragma unroll
        for (int v = 0; v < D_ / 2; ++v) {
            __half2 hv = *(const __half2*)(hc + 2 * v);
            float x0 = __low2float(hv), x1 = __high2float(hv);
            const float* w0 = Wt + (c * D_ + 2 * v) * D_;
            const float* w1 = w0 + D_;
#pragma unroll
            for (int o = 0; o < DCH; ++o) acc[o] = fmaf(x0, w0[o], acc[o]);
#pragma unroll
            for (int o = 0; o < DCH; ++o) acc[o] = fmaf(x1, w1[o], acc[o]);
        }
    }
#pragma unroll
    for (int g2 = 0; g2 < G_ / 2; ++g2) {
        union { uint u; __half2 h2; } pk;
        pk.u = ldsg[GSTRIDE_U * b + g2];
        float x0 = __low2float(pk.h2), x1 = __high2float(pk.h2);
        const float* w0 = Wt + (4 * D_ + 2 * g2) * D_;
        const float* w1 = w0 + D_;
#pragma unroll
        for (int o = 0; o < DCH; ++o) acc[o] = fmaf(x0, w0[o], acc[o]);
#pragma unroll
        for (int o = 0; o < DCH; ++o) acc[o] = fmaf(x1, w1[o], acc[o]);
    }
    float h[DCH];
    bn_tanh<DCH>(acc, g + (size_t)t * D_, be + (size_t)t * D_, o0, b, h);
    if (OUT_HALF_TERM_MAJOR) {
        __half* hout = (__half*)hout_;
        uint* dst = (uint*)(hout + ((size_t)t * B_ + b) * D_ + o0);
#pragma unroll
        for (int v = 0; v < DCH / 2; ++v) {
            union { __half2 h2; uint u; } pk;
            pk.h2 = __floats2half2_rn(h[2 * v], h[2 * v + 1]);
            dst[v] = pk.u;
        }
    } else {
        float* dst = (float*)hout_ + ((size_t)b * T + t) * D_ + o0;
#pragma unroll
        for (int o = 0; o < DCH; ++o) dst[o] = h[o];
    }
}

// ---- root GEMV: one block per batch row, K-strided over h1 (batch-major) ----
__global__ __launch_bounds__(256, 4) void k_stage0a(const float* __restrict__ h1,
                                                    const float* __restrict__ genes0,
                                                    const float* __restrict__ W0,
                                                    float* __restrict__ z0) {
    const int b = blockIdx.x, tid = threadIdx.x;
    const float* x = h1 + (size_t)b * (T1_ * D_);
    float acc[D_] = {};
#pragma unroll
    for (int jj = 0; jj < (T1_ * D_) / 256; ++jj) {
        int k = tid + jj * 256;
        float xk = x[k];
        const float4* w = (const float4*)(W0 + (size_t)k * D_);
#pragma unroll
        for (int v = 0; v < D_ / 4; ++v) {
            float4 f = w[v];
            acc[4 * v + 0] = fmaf(xk, f.x, acc[4 * v + 0]);
            acc[4 * v + 1] = fmaf(xk, f.y, acc[4 * v + 1]);
            acc[4 * v + 2] = fmaf(xk, f.z, acc[4 * v + 2]);
            acc[4 * v + 3] = fmaf(xk, f.w, acc[4 * v + 3]);
        }
    }
    if (tid < G_) {
        float xk = genes0[(size_t)b * G_ + tid];
        const float4* w = (const float4*)(W0 + (size_t)(T1_ * D_ + tid) * D_);
#pragma unroll
        for (int v = 0; v < D_ / 4; ++v) {
            float4 f = w[v];
            acc[4 * v + 0] = fmaf(xk, f.x, acc[4 * v + 0]);
            acc[4 * v + 1] = fmaf(xk, f.y, acc[4 * v + 1]);
            acc[4 * v + 2] = fmaf(xk, f.z, acc[4 * v + 2]);
            acc[4 * v + 3] = fmaf(xk, f.w, acc[4 * v + 3]);
        }
    }
    __shared__ float sred[4][D_];
    const int lane = tid & 63, wave = tid >> 6;
#pragma unroll
    for (int off = 32; off; off >>= 1)
#pragma unroll
        for (int o = 0; o < D_; ++o) acc[o] += __shfl_xor(acc[o], off, 64);
    if (lane == 0)
#pragma unroll
        for (int o = 0; o < D_; ++o) sred[wave][o] = acc[o];
    __syncthreads();
    if (tid < D_)
        z0[(size_t)b * D_ + tid] = sred[0][tid] + sred[1][tid] + sred[2][tid] + sred[3][tid];
}

// ---- root BN + tanh + head --------------------------------------------------
__global__ __launch_bounds__(256) void k_stage0b(const float* __restrict__ z0,
                                                 const float* __restrict__ g0,
                                                 const float* __restrict__ be0,
                                                 const float* __restrict__ hw0,
                                                 const float* __restrict__ hb0,
                                                 float* __restrict__ out) {
    const int tid = threadIdx.x;   // == batch row
    float acc[D_];
    const float4* zp = (const float4*)(z0 + (size_t)tid * D_);
#pragma unroll
    for (int v = 0; v < D_ / 4; ++v) {
        float4 f = zp[v];
        acc[4 * v + 0] = f.x; acc[4 * v + 1] = f.y;
        acc[4 * v + 2] = f.z; acc[4 * v + 3] = f.w;
    }
    float h[D_];
    bn_tanh<D_>(acc, g0, be0, 0, tid, h);
    __shared__ float hwv[D_ + 1];
    if (tid < D_) hwv[tid] = hw0[tid];
    if (tid == 0) hwv[D_] = hb0[0];
    __syncthreads();
    float pred = hwv[D_];
#pragma unroll
    for (int o = 0; o < D_; ++o) pred = fmaf(h[o], hwv[o], pred);
    out[tid] = pred;
}

extern "C" void kernel_launch(void* const* d_in, const int* in_sizes, int n_in,
                              void* d_out, int out_size, void* d_ws, size_t ws_size,
                              hipStream_t stream) {
    const float* genes3 = (const float*)d_in[0];
    const float* genes2 = (const float*)d_in[1];
    const float* genes1 = (const float*)d_in[2];
    const float* genes0 = (const float*)d_in[3];
    const float* W3  = (const float*)d_in[4];
    const float* g3  = (const float*)d_in[6];
    const float* be3 = (const float*)d_in[7];
    const float* W2  = (const float*)d_in[8];
    const float* g2  = (const float*)d_in[10];
    const float* be2 = (const float*)d_in[11];
    const float* W1  = (const float*)d_in[12];
    const float* g1  = (const float*)d_in[14];
    const float* be1 = (const float*)d_in[15];
    const float* W0  = (const float*)d_in[16];
    const float* g0  = (const float*)d_in[18];
    const float* be0 = (const float*)d_in[19];
    const float* hw0 = (const float*)d_in[20];
    const float* hb0 = (const float*)d_in[21];

    char* wsb = (char*)d_ws;
    __half* h3 = (__half*)(wsb + OFF_H3B);
    __half* h2 = (__half*)(wsb + OFF_H2B);
    float*  h1 = (float*)(wsb + OFF_H1B);
    float*  z0 = (float*)(wsb + OFF_Z0B);

    k_stage3<<<T3_, 256, 0, stream>>>(genes3, W3, g3, be3, h3);
    k_mid<T2_, 20, true ><<<T2_, 256, 0, stream>>>(h3, genes2, W2, g2, be2, h2);
    k_mid<T1_, 10, false><<<T1_ * 2, 256, 0, stream>>>(h2, genes1, W1, g1, be1, h1);
    k_stage0a<<<B_, 256, 0, stream>>>(h1, genes0, W0, z0);
    k_stage0b<<<1, 256, 0, stream>>>(z0, g0, be0, hw0, hb0, (float*)d_out);
}

// Round 5
// 330.434 us; speedup vs baseline: 1.2085x; 1.2085x over previous
//
#include <hip/hip_runtime.h>
#include <hip/hip_fp16.h>

// DCell forward, MI355X (gfx950). All inputs/outputs fp32.
// One block per (term, D-chunk) => BatchNorm is block-local.
// Linear bias b{3,2,1,0} cancels inside BatchNorm (z - mean) => never read.
// R5 key fix: weights are wave-uniform => compiler used s_load chains with
// lgkmcnt(0) drains at HBM latency (the ~107 us layout-invariant stall).
// Now: weights staged to LDS as packed fp16 pairs (k,k+1), consumed via
// v_dot2_f32_f16 broadcast reads (same-address => conflict-free fast path).
// Genes staged to LDS fp16 by 16-lane row-cooperative loader (256 B rows).
// ws: [h3 fp16 [t][b][D] | h2 fp16 [t][b][D] | h1 fp32 [b][t][D] | z0p] ~29 MB.

#define DEV static __device__ __forceinline__

constexpr int B_  = 256, G_ = 64, D_ = 20;
constexpr int T3_ = 2048, T2_ = 512, T1_ = 128;
constexpr float EPS_ = 1e-5f;
constexpr int INM = 4 * D_ + G_;   // 144

constexpr size_t N_H3 = (size_t)T3_ * B_ * D_;   // halfs
constexpr size_t N_H2 = (size_t)T2_ * B_ * D_;   // halfs
constexpr size_t N_H1 = (size_t)B_ * T1_ * D_;   // floats
constexpr size_t OFF_H3B = 0;
constexpr size_t OFF_H2B = OFF_H3B + N_H3 * 2;
constexpr size_t OFF_H1B = OFF_H2B + N_H2 * 2;
constexpr size_t OFF_Z0B = OFF_H1B + N_H1 * 4;   // z0p[256][4][20] fp32

constexpr int GSTRIDE_U = 33;   // gene row stride in uints; bank step 1 => free

typedef _Float16 hf2 __attribute__((ext_vector_type(2)));

DEV float dot2f(uint xu, uint wu, float c) {
#if __has_builtin(__builtin_amdgcn_fdot2)
    return __builtin_amdgcn_fdot2(__builtin_bit_cast(hf2, xu),
                                  __builtin_bit_cast(hf2, wu), c, false);
#else
    union { uint u; __half2 h; } X, W;
    X.u = xu; W.u = wu;
    c = fmaf(__low2float(X.h),  __low2float(W.h),  c);
    return fmaf(__high2float(X.h), __high2float(W.h), c);
#endif
}

DEV float fast_tanh(float x) {
    float e = __expf(2.0f * x);
    return fmaf(-2.0f, __builtin_amdgcn_rcpf(e + 1.0f), 1.0f);
}

// genes[0:256][t][0:64] fp32 -> LDS fp16; 16 lanes cover one 256 B row.
DEV void stage_genes(const float* __restrict__ genes_t, size_t rowStrideF,
                     uint* ldsg, int tid) {
    const int e = tid & 15, r0 = tid >> 4;
#pragma unroll
    for (int it = 0; it < 16; ++it) {
        const int row = r0 + 16 * it;
        float4 f = ((const float4*)(genes_t + (size_t)row * rowStrideF))[e];
        union { __half2 h2; uint u; } p0, p1;
        p0.h2 = __floats2half2_rn(f.x, f.y);
        p1.h2 = __floats2half2_rn(f.z, f.w);
        ldsg[GSTRIDE_U * row + 2 * e]     = p0.u;
        ldsg[GSTRIDE_U * row + 2 * e + 1] = p1.u;
    }
}

// Pack weights W[k][o] fp32 -> LDS uint[p][oo] = half2(W[2p][o0+oo], W[2p+1][o0+oo]).
// NP = k-pairs, DCH = o-chunk width.
template <int NP, int DCH>
DEV void stage_weights(const float* __restrict__ Wt, int o0, uint* ldsw, int tid) {
    constexpr int NU = NP * DCH;
#pragma unroll
    for (int j0 = 0; j0 < NU; j0 += 256) {
        int j = j0 + tid;
        if (NU % 256 != 0 && j >= NU) break;
        int p = j / DCH, oo = j - p * DCH;
        float w0 = Wt[(2 * p) * D_ + o0 + oo];
        float w1 = Wt[(2 * p + 1) * D_ + o0 + oo];
        union { __half2 h2; uint u; } pk;
        pk.h2 = __floats2half2_rn(w0, w1);
        ldsw[j] = pk.u;
    }
}

// BN over batch (block-local: 256 threads == 256 batch rows) + tanh.
template <int N>
DEV void bn_tanh(const float (&acc)[N], const float* gterm, const float* beterm,
                 int o0, int tid, float (&h)[N]) {
    __shared__ float sred[4][N], qred[4][N], Avec[N], Cvec[N];
    const int lane = tid & 63, wave = tid >> 6;
    float s[N], q[N];
#pragma unroll
    for (int o = 0; o < N; ++o) { s[o] = acc[o]; q[o] = acc[o] * acc[o]; }
#pragma unroll
    for (int off = 32; off; off >>= 1) {
#pragma unroll
        for (int o = 0; o < N; ++o) {
            s[o] += __shfl_xor(s[o], off, 64);
            q[o] += __shfl_xor(q[o], off, 64);
        }
    }
    if (lane == 0) {
#pragma unroll
        for (int o = 0; o < N; ++o) { sred[wave][o] = s[o]; qred[wave][o] = q[o]; }
    }
    __syncthreads();
    if (tid < N) {
        float S = sred[0][tid] + sred[1][tid] + sred[2][tid] + sred[3][tid];
        float Q = qred[0][tid] + qred[1][tid] + qred[2][tid] + qred[3][tid];
        float mu  = S * (1.0f / B_);
        float var = fmaxf(Q * (1.0f / B_) - mu * mu, 0.0f);
        float rstd = rsqrtf(var + EPS_);
        float A = rstd * gterm[o0 + tid];
        Avec[tid] = A;
        Cvec[tid] = beterm[o0 + tid] - mu * A;
    }
    __syncthreads();
#pragma unroll
    for (int o = 0; o < N; ++o) h[o] = fast_tanh(fmaf(acc[o], Avec[o], Cvec[o]));
}

// Read one packed-weight row (DCH uints) from LDS via widest aligned chunks.
template <int DCH>
DEV void load_wrow(const uint* ldsw, int p, uint (&w)[DCH]) {
    const uint* row = ldsw + p * DCH;
    if constexpr (DCH % 4 == 0) {
#pragma unroll
        for (int v = 0; v < DCH / 4; ++v) {
            uint4 u = ((const uint4*)row)[v];
            w[4 * v] = u.x; w[4 * v + 1] = u.y; w[4 * v + 2] = u.z; w[4 * v + 3] = u.w;
        }
    } else {
#pragma unroll
        for (int v = 0; v < DCH / 2; ++v) {
            uint2 u = ((const uint2*)row)[v];
            w[2 * v] = u.x; w[2 * v + 1] = u.y;
        }
    }
}

// ---- stratum 3 (leaves): x = genes (64), out fp16 term-major ----------------
__global__ __launch_bounds__(256, 4) void k_stage3(const float* __restrict__ genes,
                                                   const float* __restrict__ W,
                                                   const float* __restrict__ g,
                                                   const float* __restrict__ be,
                                                   __half* __restrict__ hout) {
    __shared__ uint ldsg[B_ * GSTRIDE_U];
    __shared__ uint ldsw[(G_ / 2) * D_];     // 32 pairs x 20
    const int t = blockIdx.x, b = threadIdx.x;
    stage_genes(genes + (size_t)t * G_, (size_t)T3_ * G_, ldsg, b);
    stage_weights<G_ / 2, D_>(W + (size_t)t * (G_ * D_), 0, ldsw, b);
    __syncthreads();
    float acc[D_] = {};
#pragma unroll
    for (int p = 0; p < G_ / 2; ++p) {
        uint xu = ldsg[GSTRIDE_U * b + p];
        uint w[D_];
        load_wrow<D_>(ldsw, p, w);
#pragma unroll
        for (int o = 0; o < D_; ++o) acc[o] = dot2f(xu, w[o], acc[o]);
    }
    float h[D_];
    bn_tanh<D_>(acc, g + (size_t)t * D_, be + (size_t)t * D_, 0, b, h);
    uint2* dst = (uint2*)(hout + ((size_t)t * B_ + b) * D_);
#pragma unroll
    for (int v = 0; v < 5; ++v) {
        union { __half2 h2[2]; uint2 u; } pk;
        pk.h2[0] = __floats2half2_rn(h[4 * v],     h[4 * v + 1]);
        pk.h2[1] = __floats2half2_rn(h[4 * v + 2], h[4 * v + 3]);
        dst[v] = pk.u;
    }
}

// ---- strata 2/1: x = [4 fp16 children (80) | genes (64)] --------------------
template <int T, int DCH, bool OUT_HALF_TERM_MAJOR>
__global__ __launch_bounds__(256, 2) void k_mid(const __half* __restrict__ hsrc,
                                                const float* __restrict__ genes,
                                                const float* __restrict__ W,
                                                const float* __restrict__ g,
                                                const float* __restrict__ be,
                                                void* __restrict__ hout_) {
    constexpr int NCH = D_ / DCH;
    constexpr int NP = INM / 2;              // 72 k-pairs (children 0..39, genes 40..71)
    __shared__ uint ldsg[B_ * GSTRIDE_U];
    __shared__ uint ldsw[NP * DCH];
    const int t = blockIdx.x / NCH, o0 = (blockIdx.x % NCH) * DCH;
    const int b = threadIdx.x;
    stage_genes(genes + (size_t)t * G_, (size_t)T * G_, ldsg, b);
    stage_weights<NP, DCH>(W + (size_t)t * (INM * D_), o0, ldsw, b);
    __syncthreads();

    float acc[DCH] = {};
#pragma unroll
    for (int c = 0; c < 4; ++c) {
        // child row: 20 halfs = 40 B per lane, lane-contiguous => coalesced
        const uint2* hp = (const uint2*)(hsrc + ((size_t)(4 * t + c) * B_ + b) * D_);
        uint xc[10];
#pragma unroll
        for (int v = 0; v < 5; ++v) {
            uint2 u = hp[v];
            xc[2 * v] = u.x; xc[2 * v + 1] = u.y;
        }
#pragma unroll
        for (int v = 0; v < 10; ++v) {
            uint w[DCH];
            load_wrow<DCH>(ldsw, c * 10 + v, w);
#pragma unroll
            for (int o = 0; o < DCH; ++o) acc[o] = dot2f(xc[v], w[o], acc[o]);
        }
    }
#pragma unroll
    for (int p = 0; p < G_ / 2; ++p) {
        uint xu = ldsg[GSTRIDE_U * b + p];
        uint w[DCH];
        load_wrow<DCH>(ldsw, 40 + p, w);
#pragma unroll
        for (int o = 0; o < DCH; ++o) acc[o] = dot2f(xu, w[o], acc[o]);
    }
    float h[DCH];
    bn_tanh<DCH>(acc, g + (size_t)t * D_, be + (size_t)t * D_, o0, b, h);
    if (OUT_HALF_TERM_MAJOR) {
        __half* hout = (__half*)hout_;
        uint* dst = (uint*)(hout + ((size_t)t * B_ + b) * D_ + o0);
#pragma unroll
        for (int v = 0; v < DCH / 2; ++v) {
            union { __half2 h2; uint u; } pk;
            pk.h2 = __floats2half2_rn(h[2 * v], h[2 * v + 1]);
            dst[v] = pk.u;
        }
    } else {
        float* dst = (float*)hout_ + ((size_t)b * T + t) * D_ + o0;
#pragma unroll
        for (int o = 0; o < DCH; ++o) dst[o] = h[o];
    }
}

// ---- root GEMV, K-split x4: grid = 256 b-rows x 4 splits --------------------
__global__ __launch_bounds__(256, 4) void k_stage0a(const float* __restrict__ h1,
                                                    const float* __restrict__ genes0,
                                                    const float* __restrict__ W0,
                                                    float* __restrict__ z0p) {
    const int b = blockIdx.x >> 2, s = blockIdx.x & 3, tid = threadIdx.x;
    const int kbase = 640 * s;
    const float* x = h1 + (size_t)b * (T1_ * D_);
    float acc[D_] = {};
#pragma unroll
    for (int j = 0; j < 3; ++j) {
        int kl = tid + 256 * j;
        if (kl < 640) {
            int k = kbase + kl;
            float xk = x[k];
            const float4* w = (const float4*)(W0 + (size_t)k * D_);
#pragma unroll
            for (int v = 0; v < D_ / 4; ++v) {
                float4 f = w[v];
                acc[4 * v + 0] = fmaf(xk, f.x, acc[4 * v + 0]);
                acc[4 * v + 1] = fmaf(xk, f.y, acc[4 * v + 1]);
                acc[4 * v + 2] = fmaf(xk, f.z, acc[4 * v + 2]);
                acc[4 * v + 3] = fmaf(xk, f.w, acc[4 * v + 3]);
            }
        }
    }
    if (s == 3 && tid < G_) {
        float xk = genes0[(size_t)b * G_ + tid];
        const float4* w = (const float4*)(W0 + (size_t)(T1_ * D_ + tid) * D_);
#pragma unroll
        for (int v = 0; v < D_ / 4; ++v) {
            float4 f = w[v];
            acc[4 * v + 0] = fmaf(xk, f.x, acc[4 * v + 0]);
            acc[4 * v + 1] = fmaf(xk, f.y, acc[4 * v + 1]);
            acc[4 * v + 2] = fmaf(xk, f.z, acc[4 * v + 2]);
            acc[4 * v + 3] = fmaf(xk, f.w, acc[4 * v + 3]);
        }
    }
    __shared__ float sred[4][D_];
    const int lane = tid & 63, wave = tid >> 6;
#pragma unroll
    for (int off = 32; off; off >>= 1)
#pragma unroll
        for (int o = 0; o < D_; ++o) acc[o] += __shfl_xor(acc[o], off, 64);
    if (lane == 0)
#pragma unroll
        for (int o = 0; o < D_; ++o) sred[wave][o] = acc[o];
    __syncthreads();
    if (tid < D_)
        z0p[((size_t)b * 4 + s) * D_ + tid] =
            sred[0][tid] + sred[1][tid] + sred[2][tid] + sred[3][tid];
}

// ---- root BN + tanh + head --------------------------------------------------
__global__ __launch_bounds__(256) void k_stage0b(const float* __restrict__ z0p,
                                                 const float* __restrict__ g0,
                                                 const float* __restrict__ be0,
                                                 const float* __restrict__ hw0,
                                                 const float* __restrict__ hb0,
                                                 float* __restrict__ out) {
    const int tid = threadIdx.x;   // == batch row
    float acc[D_] = {};
#pragma unroll
    for (int s = 0; s < 4; ++s) {
        const float4* zp = (const float4*)(z0p + ((size_t)tid * 4 + s) * D_);
#pragma unroll
        for (int v = 0; v < D_ / 4; ++v) {
            float4 f = zp[v];
            acc[4 * v + 0] += f.x; acc[4 * v + 1] += f.y;
            acc[4 * v + 2] += f.z; acc[4 * v + 3] += f.w;
        }
    }
    float h[D_];
    bn_tanh<D_>(acc, g0, be0, 0, tid, h);
    __shared__ float hwv[D_ + 1];
    if (tid < D_) hwv[tid] = hw0[tid];
    if (tid == 0) hwv[D_] = hb0[0];
    __syncthreads();
    float pred = hwv[D_];
#pragma unroll
    for (int o = 0; o < D_; ++o) pred = fmaf(h[o], hwv[o], pred);
    out[tid] = pred;
}

extern "C" void kernel_launch(void* const* d_in, const int* in_sizes, int n_in,
                              void* d_out, int out_size, void* d_ws, size_t ws_size,
                              hipStream_t stream) {
    const float* genes3 = (const float*)d_in[0];
    const float* genes2 = (const float*)d_in[1];
    const float* genes1 = (const float*)d_in[2];
    const float* genes0 = (const float*)d_in[3];
    const float* W3  = (const float*)d_in[4];
    const float* g3  = (const float*)d_in[6];
    const float* be3 = (const float*)d_in[7];
    const float* W2  = (const float*)d_in[8];
    const float* g2  = (const float*)d_in[10];
    const float* be2 = (const float*)d_in[11];
    const float* W1  = (const float*)d_in[12];
    const float* g1  = (const float*)d_in[14];
    const float* be1 = (const float*)d_in[15];
    const float* W0  = (const float*)d_in[16];
    const float* g0  = (const float*)d_in[18];
    const float* be0 = (const float*)d_in[19];
    const float* hw0 = (const float*)d_in[20];
    const float* hb0 = (const float*)d_in[21];

    char* wsb = (char*)d_ws;
    __half* h3 = (__half*)(wsb + OFF_H3B);
    __half* h2 = (__half*)(wsb + OFF_H2B);
    float*  h1 = (float*)(wsb + OFF_H1B);
    float*  z0p = (float*)(wsb + OFF_Z0B);

    k_stage3<<<T3_, 256, 0, stream>>>(genes3, W3, g3, be3, h3);
    k_mid<T2_, 20, true ><<<T2_, 256, 0, stream>>>(h3, genes2, W2, g2, be2, h2);
    k_mid<T1_, 10, false><<<T1_ * 2, 256, 0, stream>>>(h2, genes1, W1, g1, be1, h1);
    k_stage0a<<<B_ * 4, 256, 0, stream>>>(h1, genes0, W0, z0p);
    k_stage0b<<<1, 256, 0, stream>>>(z0p, g0, be0, hw0, hb0, (float*)d_out);
}